// Round 1
// baseline (3213.387 us; speedup 1.0000x reference)
//
#include <hip/hip_runtime.h>

// Masked scatter-mean: out[t, :] = mean over edges e with tgt_ids[e]==t and
// all(ntypes[e,:] >= 0) of feat[src_ids[e], :].  C = 32 channels, f32.
//
// Kernel 1: 8 threads per edge; each thread handles 4 channels (float4 gather
//           + 4 global f32 atomicAdds into the sums buffer = d_out).
//           Thread with group==0 also bumps the per-target count (in d_ws).
// Kernel 2: vectorized divide: out = cnt>0 ? sum/cnt : 0   (float4 per thread).

#define CCH 32  // channels

__global__ __launch_bounds__(256) void scatter_accum_kernel(
    const float* __restrict__ feat,
    const int* __restrict__ src_ids,
    const int* __restrict__ tgt_ids,
    const int* __restrict__ ntypes,
    float* __restrict__ sums,
    unsigned int* __restrict__ counts,
    long long total_threads) {
  long long tid = (long long)blockIdx.x * blockDim.x + threadIdx.x;
  if (tid >= total_threads) return;
  const int e = (int)(tid >> 3);   // edge index
  const int g = (int)(tid & 7);    // channel group (4 channels each)

  // mask: all three ntypes >= 0  <=>  OR of them has sign bit clear
  const long long eb = 3LL * e;
  const int n0 = ntypes[eb + 0];
  const int n1 = ntypes[eb + 1];
  const int n2 = ntypes[eb + 2];
  if ((n0 | n1 | n2) < 0) return;

  const int s = src_ids[e];
  const int t = tgt_ids[e];

  const float4 v = *reinterpret_cast<const float4*>(
      feat + (long long)s * CCH + g * 4);
  float* dst = sums + (long long)t * CCH + g * 4;
  atomicAdd(dst + 0, v.x);
  atomicAdd(dst + 1, v.y);
  atomicAdd(dst + 2, v.z);
  atomicAdd(dst + 3, v.w);
  if (g == 0) atomicAdd(counts + t, 1u);
}

__global__ __launch_bounds__(256) void finalize_kernel(
    float* __restrict__ out,
    const unsigned int* __restrict__ counts,
    int total_vec4) {  // n_tgt * 8 float4's
  int tid = blockIdx.x * blockDim.x + threadIdx.x;
  if (tid >= total_vec4) return;
  const int t = tid >> 3;  // 8 float4 per target row
  const unsigned int cnt = counts[t];
  float4* p = reinterpret_cast<float4*>(out) + tid;
  float4 v = *p;
  const float inv = (cnt > 0u) ? (1.0f / (float)cnt) : 0.0f;
  v.x *= inv; v.y *= inv; v.z *= inv; v.w *= inv;
  *p = v;
}

extern "C" void kernel_launch(void* const* d_in, const int* in_sizes, int n_in,
                              void* d_out, int out_size, void* d_ws, size_t ws_size,
                              hipStream_t stream) {
  const float* feat    = (const float*)d_in[0];
  const int*   src_ids = (const int*)d_in[1];
  const int*   tgt_ids = (const int*)d_in[2];
  const int*   ntypes  = (const int*)d_in[3];
  // d_in[4] is n_tgt on device; derive on host instead: out is [n_tgt, 32].
  const int E     = in_sizes[1];
  const int n_tgt = out_size / CCH;

  float*        sums   = (float*)d_out;
  unsigned int* counts = (unsigned int*)d_ws;  // needs n_tgt*4 bytes

  // Zero accumulation buffers every call (harness poisons once; graph replays
  // must be deterministic, so we re-zero on-stream each launch).
  hipMemsetAsync(d_out, 0, (size_t)out_size * sizeof(float), stream);
  hipMemsetAsync(d_ws, 0, (size_t)n_tgt * sizeof(unsigned int), stream);

  const long long total_threads = (long long)E * 8;
  const int block = 256;
  const long long nblocks = (total_threads + block - 1) / block;
  scatter_accum_kernel<<<(dim3)((unsigned int)nblocks), block, 0, stream>>>(
      feat, src_ids, tgt_ids, ntypes, sums, counts, total_threads);

  const int total_vec4 = n_tgt * 8;
  finalize_kernel<<<(total_vec4 + block - 1) / block, block, 0, stream>>>(
      sums, counts, total_vec4);
}

// Round 2
// 901.901 us; speedup vs baseline: 3.5629x; 3.5629x over previous
//
#include <hip/hip_runtime.h>

// Masked scatter-mean via CSR build + gather-reduce (no float atomics).
//
//  hist          : counts[t] = #valid edges with tgt==t      (int atomics, 4MB)
//  scan1/2/3     : exclusive scan counts -> offsets, cursor  (3-kernel scan)
//  scatter_ids   : csr_src[atomicAdd(cursor[t])] = src_ids[e]
//  gather_reduce : out[t,:] = mean of feat[csr_src[i],:] over i in [off[t],off[t+1])
//
// Fallback: if ws_size is too small for CSR buffers, use the R1 atomic path.

#define CCH 32  // channels

// ---------------- CSR path ----------------

__global__ __launch_bounds__(256) void hist_kernel(
    const int* __restrict__ tgt_ids, const int* __restrict__ ntypes,
    unsigned int* __restrict__ counts, int E) {
  int e = blockIdx.x * 256 + threadIdx.x;
  if (e >= E) return;
  const long long eb = 3LL * e;
  if ((ntypes[eb] | ntypes[eb + 1] | ntypes[eb + 2]) < 0) return;
  atomicAdd(&counts[tgt_ids[e]], 1u);
}

__global__ __launch_bounds__(256) void scan1_kernel(
    const unsigned int* __restrict__ counts,
    unsigned int* __restrict__ partials, int n) {
  __shared__ unsigned int sm[256];
  int i = blockIdx.x * 256 + threadIdx.x;
  unsigned int v = (i < n) ? counts[i] : 0u;
  sm[threadIdx.x] = v;
  __syncthreads();
  for (int off = 128; off > 0; off >>= 1) {
    if (threadIdx.x < (unsigned)off) sm[threadIdx.x] += sm[threadIdx.x + off];
    __syncthreads();
  }
  if (threadIdx.x == 0) partials[blockIdx.x] = sm[0];
}

__global__ __launch_bounds__(1024) void scan2_kernel(unsigned int* partials, int n) {
  // single-block exclusive scan, chunks of 1024
  __shared__ unsigned int sm[1024];
  unsigned int carry = 0;
  for (int base = 0; base < n; base += 1024) {
    int i = base + threadIdx.x;
    unsigned int v = (i < n) ? partials[i] : 0u;
    sm[threadIdx.x] = v;
    __syncthreads();
    for (int off = 1; off < 1024; off <<= 1) {
      unsigned int add = (threadIdx.x >= (unsigned)off) ? sm[threadIdx.x - off] : 0u;
      __syncthreads();
      sm[threadIdx.x] += add;
      __syncthreads();
    }
    unsigned int incl = sm[threadIdx.x];
    unsigned int total = sm[1023];
    if (i < n) partials[i] = incl - v + carry;
    carry += total;
    __syncthreads();  // protect sm before next chunk overwrites
  }
}

__global__ __launch_bounds__(256) void scan3_kernel(
    const unsigned int* __restrict__ counts,
    const unsigned int* __restrict__ partials,
    unsigned int* __restrict__ offsets,
    unsigned int* __restrict__ cursor, int n) {
  __shared__ unsigned int sm[256];
  int i = blockIdx.x * 256 + threadIdx.x;
  unsigned int v = (i < n) ? counts[i] : 0u;
  sm[threadIdx.x] = v;
  __syncthreads();
  for (int off = 1; off < 256; off <<= 1) {
    unsigned int add = (threadIdx.x >= (unsigned)off) ? sm[threadIdx.x - off] : 0u;
    __syncthreads();
    sm[threadIdx.x] += add;
    __syncthreads();
  }
  unsigned int excl = sm[threadIdx.x] - v + partials[blockIdx.x];
  if (i < n) {
    offsets[i] = excl;
    cursor[i] = excl;
    if (i == n - 1) offsets[n] = excl + v;  // grand total
  }
}

__global__ __launch_bounds__(256) void scatter_ids_kernel(
    const int* __restrict__ src_ids, const int* __restrict__ tgt_ids,
    const int* __restrict__ ntypes, unsigned int* __restrict__ cursor,
    int* __restrict__ csr_src, int E) {
  int e = blockIdx.x * 256 + threadIdx.x;
  if (e >= E) return;
  const long long eb = 3LL * e;
  if ((ntypes[eb] | ntypes[eb + 1] | ntypes[eb + 2]) < 0) return;
  unsigned int slot = atomicAdd(&cursor[tgt_ids[e]], 1u);
  csr_src[slot] = src_ids[e];
}

__global__ __launch_bounds__(256) void gather_reduce_kernel(
    const float* __restrict__ feat, const int* __restrict__ csr_src,
    const unsigned int* __restrict__ offsets, float* __restrict__ out,
    int n_tgt) {
  int tid = blockIdx.x * 256 + threadIdx.x;
  int t = tid >> 3;  // 8 threads per target
  int g = tid & 7;   // 4 channels each
  if (t >= n_tgt) return;
  unsigned int beg = offsets[t], end = offsets[t + 1];
  float4 acc = {0.f, 0.f, 0.f, 0.f};
  for (unsigned int i = beg; i < end; ++i) {
    int s = csr_src[i];
    const float4 v =
        *reinterpret_cast<const float4*>(feat + (long long)s * CCH + g * 4);
    acc.x += v.x; acc.y += v.y; acc.z += v.z; acc.w += v.w;
  }
  float inv = (end > beg) ? 1.0f / (float)(end - beg) : 0.0f;
  acc.x *= inv; acc.y *= inv; acc.z *= inv; acc.w *= inv;
  *reinterpret_cast<float4*>(out + (long long)t * CCH + g * 4) = acc;
}

// ---------------- fallback atomic path (R1) ----------------

__global__ __launch_bounds__(256) void scatter_accum_kernel(
    const float* __restrict__ feat, const int* __restrict__ src_ids,
    const int* __restrict__ tgt_ids, const int* __restrict__ ntypes,
    float* __restrict__ sums, unsigned int* __restrict__ counts,
    long long total_threads) {
  long long tid = (long long)blockIdx.x * blockDim.x + threadIdx.x;
  if (tid >= total_threads) return;
  const int e = (int)(tid >> 3);
  const int g = (int)(tid & 7);
  const long long eb = 3LL * e;
  if ((ntypes[eb] | ntypes[eb + 1] | ntypes[eb + 2]) < 0) return;
  const int s = src_ids[e];
  const int t = tgt_ids[e];
  const float4 v =
      *reinterpret_cast<const float4*>(feat + (long long)s * CCH + g * 4);
  float* dst = sums + (long long)t * CCH + g * 4;
  atomicAdd(dst + 0, v.x);
  atomicAdd(dst + 1, v.y);
  atomicAdd(dst + 2, v.z);
  atomicAdd(dst + 3, v.w);
  if (g == 0) atomicAdd(counts + t, 1u);
}

__global__ __launch_bounds__(256) void finalize_kernel(
    float* __restrict__ out, const unsigned int* __restrict__ counts,
    int total_vec4) {
  int tid = blockIdx.x * blockDim.x + threadIdx.x;
  if (tid >= total_vec4) return;
  const int t = tid >> 3;
  const unsigned int cnt = counts[t];
  float4* p = reinterpret_cast<float4*>(out) + tid;
  float4 v = *p;
  const float inv = (cnt > 0u) ? (1.0f / (float)cnt) : 0.0f;
  v.x *= inv; v.y *= inv; v.z *= inv; v.w *= inv;
  *p = v;
}

// ---------------- launch ----------------

extern "C" void kernel_launch(void* const* d_in, const int* in_sizes, int n_in,
                              void* d_out, int out_size, void* d_ws,
                              size_t ws_size, hipStream_t stream) {
  const float* feat    = (const float*)d_in[0];
  const int*   src_ids = (const int*)d_in[1];
  const int*   tgt_ids = (const int*)d_in[2];
  const int*   ntypes  = (const int*)d_in[3];
  const int E     = in_sizes[1];
  const int n_tgt = out_size / CCH;

  const int block = 256;
  const int eblocks = (E + block - 1) / block;
  const int nblk_scan = (n_tgt + block - 1) / block;

  // ws layout (all u32/int):
  //   counts[n_tgt] | offsets[n_tgt+1] | cursor[n_tgt] | partials[nblk_scan] | csr_src[E]
  const size_t need =
      ((size_t)3 * n_tgt + 1 + nblk_scan + (size_t)E) * sizeof(unsigned int);

  if (ws_size >= need) {
    unsigned int* counts   = (unsigned int*)d_ws;
    unsigned int* offsets  = counts + n_tgt;
    unsigned int* cursor   = offsets + n_tgt + 1;
    unsigned int* partials = cursor + n_tgt;
    int*          csr_src  = (int*)(partials + nblk_scan);

    hipMemsetAsync(counts, 0, (size_t)n_tgt * sizeof(unsigned int), stream);

    hist_kernel<<<eblocks, block, 0, stream>>>(tgt_ids, ntypes, counts, E);
    scan1_kernel<<<nblk_scan, block, 0, stream>>>(counts, partials, n_tgt);
    scan2_kernel<<<1, 1024, 0, stream>>>(partials, nblk_scan);
    scan3_kernel<<<nblk_scan, block, 0, stream>>>(counts, partials, offsets,
                                                  cursor, n_tgt);
    scatter_ids_kernel<<<eblocks, block, 0, stream>>>(src_ids, tgt_ids, ntypes,
                                                      cursor, csr_src, E);
    const long long gthreads = (long long)n_tgt * 8;
    const int gblocks = (int)((gthreads + block - 1) / block);
    gather_reduce_kernel<<<gblocks, block, 0, stream>>>(feat, csr_src, offsets,
                                                        (float*)d_out, n_tgt);
  } else {
    // fallback: R1 atomic path (needs only n_tgt*4 bytes of ws)
    float*        sums   = (float*)d_out;
    unsigned int* counts = (unsigned int*)d_ws;
    hipMemsetAsync(d_out, 0, (size_t)out_size * sizeof(float), stream);
    hipMemsetAsync(d_ws, 0, (size_t)n_tgt * sizeof(unsigned int), stream);
    const long long total_threads = (long long)E * 8;
    const long long nblocks = (total_threads + block - 1) / block;
    scatter_accum_kernel<<<(dim3)((unsigned int)nblocks), block, 0, stream>>>(
        feat, src_ids, tgt_ids, ntypes, sums, counts, total_threads);
    const int total_vec4 = n_tgt * 8;
    finalize_kernel<<<(total_vec4 + block - 1) / block, block, 0, stream>>>(
        sums, counts, total_vec4);
  }
}

// Round 3
// 515.245 us; speedup vs baseline: 6.2366x; 1.7504x over previous
//
#include <hip/hip_runtime.h>

// Masked scatter-mean via two-level counting sort (bucket by tgt>>11) + CSR
// gather-reduce. No float atomics; no random global 4B scatters.
//
//  bucket_hist : per-bucket valid-edge totals (LDS-aggregated)
//  bucket_scan : exclusive scan of bucket totals -> boff, cursor copy
//  bin_pairs   : tile edges in LDS; reserve per-bucket ranges (1 atomic per
//                block*bucket); write packed pairs (src<<11 | tgt&2047)
//  csr_build   : one block per bucket; LDS hist+scan of 2048 local targets;
//                scatter src into contiguous CSR window; write offsets
//  gather_reduce: out[t,:] = mean feat[csr_src[i],:], i in [off[t],off[t+1])
//
// Fallbacks by ws_size: R2 CSR path, then R1 atomic path.

#define CCH 32
#define TILE 4096
typedef unsigned int u32;

// ---------------- bucket-sort path ----------------

__global__ __launch_bounds__(256) void bucket_hist_kernel(
    const int* __restrict__ tgt_ids, const int* __restrict__ ntypes,
    u32* __restrict__ bucket_tot, int E, int NB) {
  __shared__ u32 s_cnt[512];
  for (int j = threadIdx.x; j < 512; j += 256) s_cnt[j] = 0;
  __syncthreads();
  const long long stride = (long long)gridDim.x * 256;
  for (long long e = (long long)blockIdx.x * 256 + threadIdx.x; e < E;
       e += stride) {
    const long long eb = 3LL * e;
    if ((ntypes[eb] | ntypes[eb + 1] | ntypes[eb + 2]) >= 0)
      atomicAdd(&s_cnt[((u32)tgt_ids[e]) >> 11], 1u);
  }
  __syncthreads();
  for (int j = threadIdx.x; j < NB; j += 256) {
    u32 c = s_cnt[j];
    if (c) atomicAdd(&bucket_tot[j], c);
  }
}

__global__ __launch_bounds__(512) void bucket_scan_kernel(
    const u32* __restrict__ tot, u32* __restrict__ boff,
    u32* __restrict__ bcur, int NB) {
  __shared__ u32 sm[512];
  const int tid = threadIdx.x;
  u32 v = (tid < NB) ? tot[tid] : 0u;
  sm[tid] = v;
  __syncthreads();
  for (int off = 1; off < 512; off <<= 1) {
    u32 add = (tid >= off) ? sm[tid - off] : 0u;
    __syncthreads();
    sm[tid] += add;
    __syncthreads();
  }
  if (tid < NB) {
    u32 excl = sm[tid] - v;
    boff[tid] = excl;
    bcur[tid] = excl;
    if (tid == NB - 1) boff[NB] = sm[tid];
  }
}

__global__ __launch_bounds__(256) void bin_pairs_kernel(
    const int* __restrict__ src_ids, const int* __restrict__ tgt_ids,
    const int* __restrict__ ntypes, u32* __restrict__ bcur,
    u32* __restrict__ pairs, int E, int NB) {
  __shared__ unsigned short s_b[TILE];
  __shared__ u32 s_pw[TILE];
  __shared__ u32 s_cnt[512];
  __shared__ u32 s_base[512];
  const long long base = (long long)blockIdx.x * TILE;
  for (int k = 0; k < 16; ++k) {
    const int i = threadIdx.x + k * 256;
    const long long e = base + i;
    unsigned short bb = 0xFFFFu;
    u32 pw = 0;
    if (e < E) {
      const long long eb = 3LL * e;
      if ((ntypes[eb] | ntypes[eb + 1] | ntypes[eb + 2]) >= 0) {
        const u32 t = (u32)tgt_ids[e];
        const u32 s = (u32)src_ids[e];
        bb = (unsigned short)(t >> 11);
        pw = (s << 11) | (t & 2047u);
      }
    }
    s_b[i] = bb;
    s_pw[i] = pw;
  }
  for (int j = threadIdx.x; j < 512; j += 256) s_cnt[j] = 0;
  __syncthreads();
  for (int k = 0; k < 16; ++k) {
    const int i = threadIdx.x + k * 256;
    if (s_b[i] != 0xFFFFu) atomicAdd(&s_cnt[s_b[i]], 1u);
  }
  __syncthreads();
  for (int j = threadIdx.x; j < NB; j += 256) {
    u32 c = s_cnt[j];
    s_base[j] = c ? atomicAdd(&bcur[j], c) : 0u;
    s_cnt[j] = 0;
  }
  __syncthreads();
  for (int k = 0; k < 16; ++k) {
    const int i = threadIdx.x + k * 256;
    const unsigned short bb = s_b[i];
    if (bb != 0xFFFFu) {
      u32 loc = atomicAdd(&s_cnt[bb], 1u);
      pairs[s_base[bb] + loc] = s_pw[i];
    }
  }
}

__global__ __launch_bounds__(256) void csr_build_kernel(
    const u32* __restrict__ pairs, const u32* __restrict__ boff,
    u32* __restrict__ offsets, int* __restrict__ csr_src, int n_tgt, int NB) {
  __shared__ u32 s_cnt[2048];
  __shared__ u32 s_off[2048];
  __shared__ u32 s_tt[256];
  const int b = blockIdx.x;
  const u32 g0 = boff[b], g1 = boff[b + 1];
  const int t0 = b << 11;
  const int bs = min(2048, n_tgt - t0);
  for (int j = threadIdx.x; j < 2048; j += 256) s_cnt[j] = 0;
  __syncthreads();
  for (u32 i = g0 + threadIdx.x; i < g1; i += 256)
    atomicAdd(&s_cnt[pairs[i] & 2047u], 1u);
  __syncthreads();
  const int j0 = threadIdx.x * 8;
  u32 run = 0;
  for (int k = 0; k < 8; ++k) {
    s_off[j0 + k] = run;
    run += s_cnt[j0 + k];
  }
  s_tt[threadIdx.x] = run;
  __syncthreads();
  for (int off = 1; off < 256; off <<= 1) {
    u32 add = (threadIdx.x >= off) ? s_tt[threadIdx.x - off] : 0u;
    __syncthreads();
    s_tt[threadIdx.x] += add;
    __syncthreads();
  }
  const u32 excl = threadIdx.x ? s_tt[threadIdx.x - 1] : 0u;
  for (int k = 0; k < 8; ++k) s_off[j0 + k] += excl;
  __syncthreads();
  for (int j = threadIdx.x; j < bs; j += 256) offsets[t0 + j] = g0 + s_off[j];
  if (b == NB - 1 && threadIdx.x == 0) offsets[n_tgt] = g1;
  for (int j = threadIdx.x; j < 2048; j += 256) s_cnt[j] = s_off[j];
  __syncthreads();
  for (u32 i = g0 + threadIdx.x; i < g1; i += 256) {
    const u32 pw = pairs[i];
    const u32 loc = atomicAdd(&s_cnt[pw & 2047u], 1u);
    csr_src[g0 + loc] = (int)(pw >> 11);
  }
}

__global__ __launch_bounds__(256) void gather_reduce_kernel(
    const float* __restrict__ feat, const int* __restrict__ csr_src,
    const u32* __restrict__ offsets, float* __restrict__ out, int n_tgt) {
  const int tid = blockIdx.x * 256 + threadIdx.x;
  const int t = tid >> 3;
  const int g = tid & 7;
  if (t >= n_tgt) return;
  const u32 beg = offsets[t], end = offsets[t + 1];
  float4 acc = {0.f, 0.f, 0.f, 0.f};
  for (u32 i = beg; i < end; ++i) {
    const int s = csr_src[i];
    const float4 v =
        *reinterpret_cast<const float4*>(feat + (long long)s * CCH + g * 4);
    acc.x += v.x; acc.y += v.y; acc.z += v.z; acc.w += v.w;
  }
  const float inv = (end > beg) ? 1.0f / (float)(end - beg) : 0.0f;
  acc.x *= inv; acc.y *= inv; acc.z *= inv; acc.w *= inv;
  *reinterpret_cast<float4*>(out + (long long)t * CCH + g * 4) = acc;
}

// ---------------- fallback: R2 CSR path ----------------

__global__ __launch_bounds__(256) void hist_kernel(
    const int* __restrict__ tgt_ids, const int* __restrict__ ntypes,
    u32* __restrict__ counts, int E) {
  int e = blockIdx.x * 256 + threadIdx.x;
  if (e >= E) return;
  const long long eb = 3LL * e;
  if ((ntypes[eb] | ntypes[eb + 1] | ntypes[eb + 2]) < 0) return;
  atomicAdd(&counts[tgt_ids[e]], 1u);
}

__global__ __launch_bounds__(256) void scan1_kernel(
    const u32* __restrict__ counts, u32* __restrict__ partials, int n) {
  __shared__ u32 sm[256];
  int i = blockIdx.x * 256 + threadIdx.x;
  u32 v = (i < n) ? counts[i] : 0u;
  sm[threadIdx.x] = v;
  __syncthreads();
  for (int off = 128; off > 0; off >>= 1) {
    if (threadIdx.x < (unsigned)off) sm[threadIdx.x] += sm[threadIdx.x + off];
    __syncthreads();
  }
  if (threadIdx.x == 0) partials[blockIdx.x] = sm[0];
}

__global__ __launch_bounds__(1024) void scan2_kernel(u32* partials, int n) {
  __shared__ u32 sm[1024];
  u32 carry = 0;
  for (int base = 0; base < n; base += 1024) {
    int i = base + threadIdx.x;
    u32 v = (i < n) ? partials[i] : 0u;
    sm[threadIdx.x] = v;
    __syncthreads();
    for (int off = 1; off < 1024; off <<= 1) {
      u32 add = (threadIdx.x >= (unsigned)off) ? sm[threadIdx.x - off] : 0u;
      __syncthreads();
      sm[threadIdx.x] += add;
      __syncthreads();
    }
    u32 incl = sm[threadIdx.x];
    u32 total = sm[1023];
    if (i < n) partials[i] = incl - v + carry;
    carry += total;
    __syncthreads();
  }
}

__global__ __launch_bounds__(256) void scan3_kernel(
    const u32* __restrict__ counts, const u32* __restrict__ partials,
    u32* __restrict__ offsets, u32* __restrict__ cursor, int n) {
  __shared__ u32 sm[256];
  int i = blockIdx.x * 256 + threadIdx.x;
  u32 v = (i < n) ? counts[i] : 0u;
  sm[threadIdx.x] = v;
  __syncthreads();
  for (int off = 1; off < 256; off <<= 1) {
    u32 add = (threadIdx.x >= (unsigned)off) ? sm[threadIdx.x - off] : 0u;
    __syncthreads();
    sm[threadIdx.x] += add;
    __syncthreads();
  }
  u32 excl = sm[threadIdx.x] - v + partials[blockIdx.x];
  if (i < n) {
    offsets[i] = excl;
    cursor[i] = excl;
    if (i == n - 1) offsets[n] = excl + v;
  }
}

__global__ __launch_bounds__(256) void scatter_ids_kernel(
    const int* __restrict__ src_ids, const int* __restrict__ tgt_ids,
    const int* __restrict__ ntypes, u32* __restrict__ cursor,
    int* __restrict__ csr_src, int E) {
  int e = blockIdx.x * 256 + threadIdx.x;
  if (e >= E) return;
  const long long eb = 3LL * e;
  if ((ntypes[eb] | ntypes[eb + 1] | ntypes[eb + 2]) < 0) return;
  u32 slot = atomicAdd(&cursor[tgt_ids[e]], 1u);
  csr_src[slot] = src_ids[e];
}

// ---------------- fallback: R1 atomic path ----------------

__global__ __launch_bounds__(256) void scatter_accum_kernel(
    const float* __restrict__ feat, const int* __restrict__ src_ids,
    const int* __restrict__ tgt_ids, const int* __restrict__ ntypes,
    float* __restrict__ sums, u32* __restrict__ counts,
    long long total_threads) {
  long long tid = (long long)blockIdx.x * blockDim.x + threadIdx.x;
  if (tid >= total_threads) return;
  const int e = (int)(tid >> 3);
  const int g = (int)(tid & 7);
  const long long eb = 3LL * e;
  if ((ntypes[eb] | ntypes[eb + 1] | ntypes[eb + 2]) < 0) return;
  const int s = src_ids[e];
  const int t = tgt_ids[e];
  const float4 v =
      *reinterpret_cast<const float4*>(feat + (long long)s * CCH + g * 4);
  float* dst = sums + (long long)t * CCH + g * 4;
  atomicAdd(dst + 0, v.x);
  atomicAdd(dst + 1, v.y);
  atomicAdd(dst + 2, v.z);
  atomicAdd(dst + 3, v.w);
  if (g == 0) atomicAdd(counts + t, 1u);
}

__global__ __launch_bounds__(256) void finalize_kernel(
    float* __restrict__ out, const u32* __restrict__ counts, int total_vec4) {
  int tid = blockIdx.x * blockDim.x + threadIdx.x;
  if (tid >= total_vec4) return;
  const int t = tid >> 3;
  const u32 cnt = counts[t];
  float4* p = reinterpret_cast<float4*>(out) + tid;
  float4 v = *p;
  const float inv = (cnt > 0u) ? (1.0f / (float)cnt) : 0.0f;
  v.x *= inv; v.y *= inv; v.z *= inv; v.w *= inv;
  *p = v;
}

// ---------------- launch ----------------

extern "C" void kernel_launch(void* const* d_in, const int* in_sizes, int n_in,
                              void* d_out, int out_size, void* d_ws,
                              size_t ws_size, hipStream_t stream) {
  const float* feat    = (const float*)d_in[0];
  const int*   src_ids = (const int*)d_in[1];
  const int*   tgt_ids = (const int*)d_in[2];
  const int*   ntypes  = (const int*)d_in[3];
  const int E     = in_sizes[1];
  const int n_src = in_sizes[0] / CCH;
  const int n_tgt = out_size / CCH;

  const int block = 256;
  const int NB = (n_tgt + 2047) >> 11;

  // bucket-path ws layout (u32):
  //   bucket_tot[NB] | boff[NB+1] | bcur[NB] | offsets[n_tgt+1] | pairs[E] | csr_src[E]
  const size_t need_bucket =
      ((size_t)3 * NB + 1 + (size_t)n_tgt + 1 + 2 * (size_t)E) * sizeof(u32);
  const int nblk_scan = (n_tgt + block - 1) / block;
  const size_t need_csr =
      ((size_t)3 * n_tgt + 1 + nblk_scan + (size_t)E) * sizeof(u32);

  if (ws_size >= need_bucket && NB <= 512 && n_src <= (1 << 21)) {
    u32* bucket_tot = (u32*)d_ws;
    u32* boff       = bucket_tot + NB;
    u32* bcur       = boff + NB + 1;
    u32* offsets    = bcur + NB;
    u32* pairs      = offsets + n_tgt + 1;
    int* csr_src    = (int*)(pairs + E);

    hipMemsetAsync(bucket_tot, 0, (size_t)NB * sizeof(u32), stream);
    bucket_hist_kernel<<<2048, block, 0, stream>>>(tgt_ids, ntypes, bucket_tot,
                                                   E, NB);
    bucket_scan_kernel<<<1, 512, 0, stream>>>(bucket_tot, boff, bcur, NB);
    const int p1blocks = (E + TILE - 1) / TILE;
    bin_pairs_kernel<<<p1blocks, block, 0, stream>>>(src_ids, tgt_ids, ntypes,
                                                     bcur, pairs, E, NB);
    csr_build_kernel<<<NB, block, 0, stream>>>(pairs, boff, offsets, csr_src,
                                               n_tgt, NB);
    const long long gthreads = (long long)n_tgt * 8;
    const int gblocks = (int)((gthreads + block - 1) / block);
    gather_reduce_kernel<<<gblocks, block, 0, stream>>>(feat, csr_src, offsets,
                                                        (float*)d_out, n_tgt);
  } else if (ws_size >= need_csr) {
    u32* counts   = (u32*)d_ws;
    u32* offsets  = counts + n_tgt;
    u32* cursor   = offsets + n_tgt + 1;
    u32* partials = cursor + n_tgt;
    int* csr_src  = (int*)(partials + nblk_scan);

    hipMemsetAsync(counts, 0, (size_t)n_tgt * sizeof(u32), stream);
    const int eblocks = (E + block - 1) / block;
    hist_kernel<<<eblocks, block, 0, stream>>>(tgt_ids, ntypes, counts, E);
    scan1_kernel<<<nblk_scan, block, 0, stream>>>(counts, partials, n_tgt);
    scan2_kernel<<<1, 1024, 0, stream>>>(partials, nblk_scan);
    scan3_kernel<<<nblk_scan, block, 0, stream>>>(counts, partials, offsets,
                                                  cursor, n_tgt);
    scatter_ids_kernel<<<eblocks, block, 0, stream>>>(src_ids, tgt_ids, ntypes,
                                                      cursor, csr_src, E);
    const long long gthreads = (long long)n_tgt * 8;
    const int gblocks = (int)((gthreads + block - 1) / block);
    gather_reduce_kernel<<<gblocks, block, 0, stream>>>(feat, csr_src, offsets,
                                                        (float*)d_out, n_tgt);
  } else {
    float* sums   = (float*)d_out;
    u32*   counts = (u32*)d_ws;
    hipMemsetAsync(d_out, 0, (size_t)out_size * sizeof(float), stream);
    hipMemsetAsync(d_ws, 0, (size_t)n_tgt * sizeof(u32), stream);
    const long long total_threads = (long long)E * 8;
    const long long nblocks = (total_threads + block - 1) / block;
    scatter_accum_kernel<<<(dim3)((unsigned int)nblocks), block, 0, stream>>>(
        feat, src_ids, tgt_ids, ntypes, sums, counts, total_threads);
    const int total_vec4 = n_tgt * 8;
    finalize_kernel<<<(total_vec4 + block - 1) / block, block, 0, stream>>>(
        sums, counts, total_vec4);
  }
}